// Round 19
// baseline (63.434 us; speedup 1.0000x reference)
//
#include <hip/hip_runtime.h>
#include <math.h>

// TopK router via MFMA: logits = x @ W^T + b ; top-2 over E=64 ; sparse softmax.
// x: [T=16384, D=2048] f32, W: [64, 2048] f32, b: [64] f32.
// d_out: [T*64] router probs f32, then [T*2] top-k indices as f32.
//
// R19: wave-owns-kslice. R13 runs at sum-of-pipes (~1290 cyc/block-chunk;
// itemized B 384 + A-LDS 288 + MFMA 233 + cvt 152 + dsw 72 + x 64); the
// expert-split makes 4 waves re-read the SAME A fragments (4x LDS) and
// re-fetch B per 16 tokens. Now: 512-thr block, TB=32, 8 waves; wave w
// owns kstep w of each 256-k chunk and computes ALL 64 experts x 32
// tokens. A read once per element (LDS /4), B per-token traffic halved
// (grid 512), MFMA/cvt unchanged -> sum ~0.6x => predict 35-45 us.
// Numerics: same cvt8 split + 6-product order; fp32 chains now 48 (<96,
// safer); f32 partials, f64 8-way merge + bias (R14 pattern). k-partition
// changes summation order: absmax no longer exactly 0, error <= R13.
// Sentinels: VGPR <= 128 & WRITE ~4.2 MB (no spill); absmax small.

#define RD 2048
#define RE 64
#define TB 32                    // tokens per block
#define NCH 8                    // chunks of 256 k

typedef __attribute__((ext_vector_type(8))) short bf16x8;
typedef __attribute__((ext_vector_type(4))) float f32x4;
typedef __attribute__((ext_vector_type(4))) unsigned int u32x4;

__device__ __forceinline__ unsigned short f2b(float f) {  // RNE f32->bf16 bits
    unsigned int u = __float_as_uint(f);
    unsigned int r = ((u >> 16) & 1u) + 0x7fffu;
    return (unsigned short)((u + r) >> 16);
}
__device__ __forceinline__ float b2f(unsigned short h) {
    return __uint_as_float(((unsigned int)h) << 16);
}

// split 8 consecutive-k floats -> packed bf16 h/l/l2 (4 dwords each)
__device__ __forceinline__ void cvt8(const f32x4 a, const f32x4 bq,
                                     unsigned int* h, unsigned int* l,
                                     unsigned int* l2) {
    float v[8] = {a.x, a.y, a.z, a.w, bq.x, bq.y, bq.z, bq.w};
#pragma unroll
    for (int j = 0; j < 4; ++j) {
        const float a0 = v[2 * j], a1 = v[2 * j + 1];
        const unsigned short h0 = f2b(a0); const float r0 = a0 - b2f(h0);
        const unsigned short h1 = f2b(a1); const float r1 = a1 - b2f(h1);
        const unsigned short m0 = f2b(r0); const float s0 = r0 - b2f(m0);
        const unsigned short m1 = f2b(r1); const float s1 = r1 - b2f(m1);
        const unsigned short q0 = f2b(s0);
        const unsigned short q1 = f2b(s1);
        h[j]  = (unsigned int)h0 | ((unsigned int)h1 << 16);
        l[j]  = (unsigned int)m0 | ((unsigned int)m1 << 16);
        l2[j] = (unsigned int)q0 | ((unsigned int)q1 << 16);
    }
}

// ---------- prep: W -> 3-way bf16 B-fragments (identical to R10-R18) ----------
// WB dword layout: ((ks*4 + et)*3 + comp)*256 + lane*4   (64 ks total)
__global__ __launch_bounds__(256) void wprep_kernel(
    const float* __restrict__ W, unsigned int* __restrict__ WB)
{
    const int ks = blockIdx.x;            // 0..63
    const int et = threadIdx.x >> 6;      // 0..3
    const int lane = threadIdx.x & 63;
    const int e = et * 16 + (lane & 15);
    const int k0 = ks * 32 + (lane >> 4) * 8;
    const float* src = W + (size_t)e * RD + k0;
    const f32x4 a = *(const f32x4*)(src);
    const f32x4 bq = *(const f32x4*)(src + 4);
    unsigned int h[4], l[4], l2[4];
    cvt8(a, bq, h, l, l2);
    unsigned int* dst = WB + (size_t)((ks * 4 + et) * 3) * 256 + lane * 4;
    *(u32x4*)(dst)       = *(u32x4*)h;
    *(u32x4*)(dst + 256) = *(u32x4*)l;
    *(u32x4*)(dst + 512) = *(u32x4*)l2;
}

// ---------- main ----------
__global__ __launch_bounds__(512, 2) void topk_router_kernel(
    const float* __restrict__ x,
    const unsigned int* __restrict__ WB,
    const float* __restrict__ b,
    float* __restrict__ out_router,
    float* __restrict__ out_idx,
    int total_tokens)
{
    const int tid = threadIdx.x;
    const int lane = tid & 63;
    const int wv = __builtin_amdgcn_readfirstlane(tid >> 6);  // kstep owner 0..7
    const int tok0 = blockIdx.x * TB;

    // A-fragment LDS: FR[kstep 8][comp 3][fl 128][4 dwords] = 48 KB.
    // fl = (tok>>4)*64 + kgroup*16 + (tok&15); frag read: fl = tt*64 + lane.
    // Aliased as PS f32[8][16][66] (33.8 KB) for the partial combine.
    __shared__ __align__(16) unsigned int FR[8][3][128][4];

    // staging: thread t -> token t&31, k-segment (t>>5)*16 .. +16 of chunk
    const int stok = tid & 31;
    const int seg  = tid >> 5;            // 0..15
    const int s_ks = seg >> 1;            // kstep 0..7
    const int s_h  = seg & 1;             // kgroup pair (0-1 or 2-3)
    const int tmax = total_tokens - 1;
    const float* gsrc = x + (size_t)min(tok0 + stok, tmax) * RD + seg * 16;
    const int fl0 = (stok >> 4) * 64 + (s_h * 2 + 0) * 16 + (stok & 15);
    const int fl1 = fl0 + 16;

    // acc[etile][toktile] -- all indices compile-time under full unroll
    f32x4 acc[4][2];
#pragma unroll
    for (int et = 0; et < 4; ++et) {
        acc[et][0] = (f32x4){0.f, 0.f, 0.f, 0.f};
        acc[et][1] = (f32x4){0.f, 0.f, 0.f, 0.f};
    }

    // prologue: load chunk 0 (16 floats = 4 f32x4 per thread)
    f32x4 p0 = *(const f32x4*)(gsrc + 0);
    f32x4 p1 = *(const f32x4*)(gsrc + 4);
    f32x4 p2 = *(const f32x4*)(gsrc + 8);
    f32x4 p3 = *(const f32x4*)(gsrc + 12);

#pragma unroll 1
    for (int c = 0; c < NCH; ++c) {
        // prefetch next chunk
        const int cn = (c + 1 < NCH) ? (c + 1) : 0;
        const f32x4 n0 = *(const f32x4*)(gsrc + (size_t)cn * 256 + 0);
        const f32x4 n1 = *(const f32x4*)(gsrc + (size_t)cn * 256 + 4);
        const f32x4 n2 = *(const f32x4*)(gsrc + (size_t)cn * 256 + 8);
        const f32x4 n3 = *(const f32x4*)(gsrc + (size_t)cn * 256 + 12);

        __syncthreads();   // all waves done reading FR of chunk c-1

        // cvt + frag store: kgroups s_h*2 (k+0..7) and s_h*2+1 (k+8..15)
        {
            unsigned int h[4], l[4], q[4];
            cvt8(p0, p1, h, l, q);
            *(u32x4*)&FR[s_ks][0][fl0][0] = *(u32x4*)h;
            *(u32x4*)&FR[s_ks][1][fl0][0] = *(u32x4*)l;
            *(u32x4*)&FR[s_ks][2][fl0][0] = *(u32x4*)q;
            cvt8(p2, p3, h, l, q);
            *(u32x4*)&FR[s_ks][0][fl1][0] = *(u32x4*)h;
            *(u32x4*)&FR[s_ks][1][fl1][0] = *(u32x4*)l;
            *(u32x4*)&FR[s_ks][2][fl1][0] = *(u32x4*)q;
        }
        __syncthreads();   // frags of chunk c visible

        // this wave's A frags (read ONCE, reused across all 4 etiles)
        const bf16x8 A0h = *(const bf16x8*)&FR[wv][0][lane][0];
        const bf16x8 A0l = *(const bf16x8*)&FR[wv][1][lane][0];
        const bf16x8 A0q = *(const bf16x8*)&FR[wv][2][lane][0];
        const bf16x8 A1h = *(const bf16x8*)&FR[wv][0][64 + lane][0];
        const bf16x8 A1l = *(const bf16x8*)&FR[wv][1][64 + lane][0];
        const bf16x8 A1q = *(const bf16x8*)&FR[wv][2][64 + lane][0];

        const int ksg = c * 8 + wv;
#pragma unroll
        for (int et = 0; et < 4; ++et) {
            const unsigned int* wp =
                WB + (size_t)((ksg * 4 + et) * 3) * 256 + lane * 4;
            const bf16x8 Bh = *(const bf16x8*)(wp);
            const bf16x8 Bl = *(const bf16x8*)(wp + 256);
            const bf16x8 Bq = *(const bf16x8*)(wp + 512);
            // canonical 6-product order (hh,hl,lh,ll,hq,qh), both tok tiles
            f32x4 a0 = acc[et][0];
            a0 = __builtin_amdgcn_mfma_f32_16x16x32_bf16(A0h, Bh, a0, 0, 0, 0);
            a0 = __builtin_amdgcn_mfma_f32_16x16x32_bf16(A0h, Bl, a0, 0, 0, 0);
            a0 = __builtin_amdgcn_mfma_f32_16x16x32_bf16(A0l, Bh, a0, 0, 0, 0);
            a0 = __builtin_amdgcn_mfma_f32_16x16x32_bf16(A0l, Bl, a0, 0, 0, 0);
            a0 = __builtin_amdgcn_mfma_f32_16x16x32_bf16(A0h, Bq, a0, 0, 0, 0);
            a0 = __builtin_amdgcn_mfma_f32_16x16x32_bf16(A0q, Bh, a0, 0, 0, 0);
            acc[et][0] = a0;
            f32x4 a1 = acc[et][1];
            a1 = __builtin_amdgcn_mfma_f32_16x16x32_bf16(A1h, Bh, a1, 0, 0, 0);
            a1 = __builtin_amdgcn_mfma_f32_16x16x32_bf16(A1h, Bl, a1, 0, 0, 0);
            a1 = __builtin_amdgcn_mfma_f32_16x16x32_bf16(A1l, Bh, a1, 0, 0, 0);
            a1 = __builtin_amdgcn_mfma_f32_16x16x32_bf16(A1l, Bl, a1, 0, 0, 0);
            a1 = __builtin_amdgcn_mfma_f32_16x16x32_bf16(A1h, Bq, a1, 0, 0, 0);
            a1 = __builtin_amdgcn_mfma_f32_16x16x32_bf16(A1q, Bh, a1, 0, 0, 0);
            acc[et][1] = a1;
        }

        p0 = n0; p1 = n1; p2 = n2; p3 = n3;
    }

    // ---- combine 8 k-slice partials (f32 via LDS, f64 merge) ----
    __syncthreads();
    float* PS = (float*)&FR[0][0][0][0];   // [8 kslice][16 tok][66]
    const double bias = (double)b[lane];

#pragma unroll
    for (int ph = 0; ph < 2; ++ph) {       // token half: ph*16 .. ph*16+15
#pragma unroll
        for (int et = 0; et < 4; ++et) {
#pragma unroll
            for (int r = 0; r < 4; ++r) {
                const int t16 = (lane >> 4) * 4 + r;      // C/D row
                const int e = et * 16 + (lane & 15);      // C/D col
                PS[(size_t)(wv * 16 + t16) * 66 + e] = acc[et][ph][r];
            }
        }
        __syncthreads();

        // wave wv handles tokens ph*16 + wv*2 + {0,1}
#pragma unroll 1
        for (int i = 0; i < 2; ++i) {
            const int tloc = wv * 2 + i;
            const int token = tok0 + ph * 16 + tloc;
            double v = bias;
#pragma unroll
            for (int q = 0; q < 8; ++q)
                v += (double)PS[(size_t)(q * 16 + tloc) * 66 + lane];

            // argmax #1 (value desc, tie -> lower lane)
            double bestv = v;
            int besti = lane;
#pragma unroll
            for (int off = 32; off > 0; off >>= 1) {
                double ov = __shfl_xor(bestv, off, 64);
                int oi = __shfl_xor(besti, off, 64);
                if (ov > bestv || (ov == bestv && oi < besti)) { bestv = ov; besti = oi; }
            }

            // argmax #2 excluding winner
            double v2 = (lane == besti) ? -INFINITY : v;
            double best2v = v2;
            int best2i = lane;
#pragma unroll
            for (int off = 32; off > 0; off >>= 1) {
                double ov = __shfl_xor(best2v, off, 64);
                int oi = __shfl_xor(best2i, off, 64);
                if (ov > best2v || (ov == best2v && oi < best2i)) { best2v = ov; best2i = oi; }
            }

            // 2-element softmax; all other experts exactly 0
            const float e2 = expf((float)(best2v - bestv));
            const float denom = 1.0f + e2;
            const float p1v = 1.0f / denom;
            const float p2v = e2 / denom;

            if (token < total_tokens) {
                float outv = 0.0f;
                if (lane == besti) outv = p1v;
                else if (lane == best2i) outv = p2v;
                out_router[(size_t)token * RE + lane] = outv;
                if (lane == 0) {
                    out_idx[(size_t)token * 2 + 0] = (float)besti;
                    out_idx[(size_t)token * 2 + 1] = (float)best2i;
                }
            }
        }
        __syncthreads();   // protect PS before next phase overwrites
    }
}

extern "C" void kernel_launch(void* const* d_in, const int* in_sizes, int n_in,
                              void* d_out, int out_size, void* d_ws, size_t ws_size,
                              hipStream_t stream) {
    const float* x = (const float*)d_in[0];
    const float* W = (const float*)d_in[1];
    const float* b = (const float*)d_in[2];

    const int E = in_sizes[2];                 // 64
    const int D = in_sizes[1] / E;             // 2048
    const int T = in_sizes[0] / D;             // 16384
    (void)E; (void)D;

    unsigned int* WB = (unsigned int*)d_ws;    // 64*4*3*1024 B = 768 KB
    float* out_router = (float*)d_out;
    float* out_idx = out_router + (size_t)T * RE;

    wprep_kernel<<<64, 256, 0, stream>>>(W, WB);

    const int grid = (T + TB - 1) / TB;        // 512
    topk_router_kernel<<<grid, 512, 0, stream>>>(x, WB, b, out_router, out_idx, T);
}